// Round 3
// baseline (94.731 us; speedup 1.0000x reference)
//
#include <hip/hip_runtime.h>
#include <math.h>

#define NB     64
#define NPTS   8192
#define S2D    384
#define GW     128
#define QROWS  32                 // rows of the 128-row grid per block
#define BLK    1024
#define PPT    8                  // points per thread (2 x float4)
#define ACCN   (QROWS * GW * 3)   // 12288 floats = 48 KB

// One block per (batch, quarter-of-grid). Phase 1: vectorized float4 preload of
// pc1 AND feat (unconditional -- all 4 quarter-blocks touch the same cache
// lines anyway), lattice computation with faithful fp32 semantics, per-batch
// offset min. Phase 2: LDS scatter-accumulate (ds_add_f32). Phase 3: coalesced
// float4 writeout fully overwriting the output (no memset needed).
__global__ __launch_bounds__(1024) void fused_splat(const float* __restrict__ pc1,
                                                    const float* __restrict__ feat,
                                                    const float* __restrict__ tm,
                                                    float* __restrict__ out) {
    const int b   = blockIdx.x >> 2;
    const int q   = blockIdx.x & 3;
    const int tid = threadIdx.x;

    __shared__ __align__(16) float acc[ACCN];
    __shared__ int s_off[2];

    if (tid < 2) s_off[tid] = 0x7FFFFFFF;
#pragma unroll
    for (int i = 0; i < ACCN / BLK; i++)
        acc[tid + i * BLK] = 0.0f;

    float t[9];
#pragma unroll
    for (int i = 0; i < 9; i++) t[i] = tm[b * 9 + i];

    // ---- vectorized preload: point-group k covers n = k*4096 + tid*4 + e
    const float4* __restrict__ pc4 = (const float4*)(pc1  + (size_t)b * 3 * NPTS);
    const float4* __restrict__ ft4 = (const float4*)(feat + (size_t)b * 3 * NPTS);

    float p0[PPT], p1[PPT], p2[PPT], f0[PPT], f1[PPT], f2[PPT];
#pragma unroll
    for (int k = 0; k < 2; k++) {
        const int base = k * 1024 + tid;
        ((float4*)p0)[k] = pc4[0 * 2048 + base];
        ((float4*)p1)[k] = pc4[1 * 2048 + base];
        ((float4*)p2)[k] = pc4[2 * 2048 + base];
        ((float4*)f0)[k] = ft4[0 * 2048 + base];
        ((float4*)f1)[k] = ft4[1 * 2048 + base];
        ((float4*)f2)[k] = ft4[2 * 2048 + base];
    }

    int gi0[PPT], gi1[PPT];
    int m0 = 0x7FFFFFFF, m1 = 0x7FFFFFFF;

    // ---- Phase 1: lattice computation (faithful fp32 semantics) + offset min
#pragma unroll
    for (int j = 0; j < PPT; j++) {
        float g[3], v[3];
#pragma unroll
        for (int i = 0; i < 3; i++) {
            // fma-ascending 3-term dot, correctly-rounded /3, round-half-even
            float e  = fmaf(t[i*3+2], p2[j], fmaf(t[i*3+1], p1[j], t[i*3+0] * p0[j]));
            float qq = __fdiv_rn(e, 3.0f);
            g[i] = rintf(qq) * 3.0f;      // exact in fp32 at this magnitude
            v[i] = e - g[i];              // exact (Sterbenz)
        }

        int rank[3];
#pragma unroll
        for (int i = 0; i < 3; i++) {
            int r = 0;
#pragma unroll
            for (int jj = 0; jj < 3; jj++)
                if (v[jj] > v[i] || (v[jj] == v[i] && jj < i)) r++;
            rank[i] = r;
        }

        const float rs_f = __fdiv_rn(g[0] + g[1] + g[2], 3.0f);  // exact int
        const int   rs   = (int)rs_f;

#pragma unroll
        for (int i = 0; i < 2; i++) {     // only lattice channels 0,1 matter
            const float rank_f = (float)rank[i];
            const bool cond = ((rank_f >= 3.0f - rs_f) && (rs_f > 0.0f)) ||
                              ((rank_f <  -rs_f)       && (rs_f < 0.0f));
            const float sign  = (rs_f > 0.0f ? -1.0f : 0.0f) + (rs_f < 0.0f ? 1.0f : 0.0f);
            const float shift = 3.0f * sign * (cond ? 1.0f : 0.0f);
            const int gi = (int)(g[i] + shift);
            const int rfin = rank[i] + (int)shift + rs;
            // CANONICAL row-min is {0,-1,-2} for clamped rank (JAX gather clamps)
            const int cand = gi - min(max(rfin, 0), 2);
            if (i == 0) { gi0[j] = gi; m0 = min(m0, cand); }
            else        { gi1[j] = gi; m1 = min(m1, cand); }
        }
    }

    // wave64 min-reduction, then cross-wave via LDS atomicMin
#pragma unroll
    for (int off = 32; off > 0; off >>= 1) {
        m0 = min(m0, __shfl_down(m0, off));
        m1 = min(m1, __shfl_down(m1, off));
    }
    if ((tid & 63) == 0) {
        atomicMin(&s_off[0], m0);
        atomicMin(&s_off[1], m1);
    }
    __syncthreads();

    const int off0 = s_off[0], off1 = s_off[1];
    const int pp0 = ((-off0) % 3 + 3) % 3;
    const int pp1 = ((-off1) % 3 + 3) % 3;
    const int rlo = q * QROWS, rhi = rlo + QROWS;

    // ---- Phase 2: LDS scatter-accumulate this block's quarter
#pragma unroll
    for (int j = 0; j < PPT; j++) {
        const int c0 = gi0[j] - off0;     // >= 0 (offset is a true min)
        const int c1 = gi1[j] - off1;
        if (c0 < S2D && c1 < S2D) {
            const int i0 = (c0 - pp0) / 3;   // exact: c0 ≡ pp0 (mod 3)
            if (i0 >= rlo && i0 < rhi) {
                const int j0 = (c1 - pp1) / 3;
                float* dst = acc + (((i0 - rlo) * GW) + j0) * 3;
                atomicAdd(dst + 0, f0[j]);
                atomicAdd(dst + 1, f1[j]);
                atomicAdd(dst + 2, f2[j]);
            }
        }
    }
    __syncthreads();

    // ---- Phase 3: coalesced writeout (fully overwrites -> no memset)
    float4* __restrict__ dst4 = (float4*)(out + ((size_t)b * GW + rlo) * GW * 3);
    const float4* __restrict__ src4 = (const float4*)acc;
#pragma unroll
    for (int i = 0; i < ACCN / (4 * BLK); i++)   // 3 float4 per thread
        dst4[tid + i * BLK] = src4[tid + i * BLK];
}

extern "C" void kernel_launch(void* const* d_in, const int* in_sizes, int n_in,
                              void* d_out, int out_size, void* d_ws, size_t ws_size,
                              hipStream_t stream) {
    const float* pc1  = (const float*)d_in[0];   // [64,3,8192]
    const float* feat = (const float*)d_in[1];   // [64,3,8192]
    const float* tm   = (const float*)d_in[2];   // [64,3,3]
    float* out = (float*)d_out;                  // [64,128,128,3]

    fused_splat<<<NB * 4, BLK, 0, stream>>>(pc1, feat, tm, out);
}